// Round 22
// baseline (263.076 us; speedup 1.0000x reference)
//
#include <hip/hip_runtime.h>

// MsCorrBlock: B=8 T=8 C=256 PL=64 CR=16 H=W=56 HW=3136 NT=64 PS=7 KK=49
// Output dtype: FLOAT32 (205,520,896 B). BNI = 1/sqrt(1+1e-5).

#define MSC_BNI 0.9999950000374997f

typedef __attribute__((ext_vector_type(8))) short bf16x8;
typedef __attribute__((ext_vector_type(4))) float f32x4;
struct __align__(8) ush4 { unsigned short v[4]; };

static __device__ __forceinline__ float b2f(unsigned short h) {
  return __uint_as_float(((unsigned int)h) << 16);
}
static __device__ __forceinline__ unsigned short f2b(float f) {
  unsigned int u = __float_as_uint(f);
  u = u + 0x7FFFu + ((u >> 16) & 1u);   // round to nearest even
  return (unsigned short)(u >> 16);
}

// K0: pack bf16 MFMA A-fragments (convention validated rounds 11-21):
//   Wt2f [tap9][kc2][m4][lane64][e8]: w2[o=m*16+(l&15)][c=kc*32+(l>>4)*8+e][tap]
//   Wt3f [kc2][m16][lane64][e8]:      w3[o][c]
//   Wt1f [kc8][m4][lane64][e8]:       w1[o][c]
//   Wt4f [kc2][m4][lane64][e8]:      w22[o][c] (c>=49 -> 0)
//   Wt5f [kc2][lane64][e8]:          w21[o=l&15][c=kc*32+(l>>4)*8+e]  (M=16)
__global__ __launch_bounds__(256) void k0_prep(
    const float* w1, const float* w2, const float* w3, const float* w22,
    const float* w21,
    unsigned short* Wt1f, unsigned short* Wt2f, unsigned short* Wt3f,
    unsigned short* Wt4f, unsigned short* Wt5f) {
  int idx = blockIdx.x * 256 + threadIdx.x;
  if (idx < 36864) {
    int j = idx;
    int e = j & 7;
    int lane = (j >> 3) & 63;
    int m = (j >> 9) & 3;
    int kc = (j >> 11) & 1;
    int tap = j >> 12;                       // 0..8
    int o = m * 16 + (lane & 15);
    int c = kc * 32 + (lane >> 4) * 8 + e;
    Wt2f[j] = f2b(w2[(o * 64 + c) * 9 + tap]);
  } else if (idx < 36864 + 16384) {
    int j = idx - 36864;
    int e = j & 7;
    int lane = (j >> 3) & 63;
    int m = (j >> 9) & 15;
    int kc = j >> 13;                        // 0..1
    int o = m * 16 + (lane & 15);
    int c = kc * 32 + (lane >> 4) * 8 + e;
    Wt3f[j] = f2b(w3[o * 64 + c]);
  } else if (idx < 36864 + 16384 + 16384) {
    int j = idx - 36864 - 16384;
    int e = j & 7;
    int lane = (j >> 3) & 63;
    int m = (j >> 9) & 3;
    int kc = j >> 11;                        // 0..7
    int o = m * 16 + (lane & 15);
    int c = kc * 32 + (lane >> 4) * 8 + e;
    Wt1f[j] = f2b(w1[o * 256 + c]);
  } else if (idx < 36864 + 16384 + 16384 + 4096) {
    int j = idx - 36864 - 16384 - 16384;
    int e = j & 7;
    int lane = (j >> 3) & 63;
    int m = (j >> 9) & 3;
    int kc = j >> 11;                        // 0..1
    int o = m * 16 + (lane & 15);
    int c = kc * 32 + (lane >> 4) * 8 + e;
    Wt4f[j] = (c < 49) ? f2b(w22[o * 49 + c]) : (unsigned short)0;
  } else if (idx < 36864 + 16384 + 16384 + 4096 + 1024) {
    int j = idx - 36864 - 16384 - 16384 - 4096;
    int e = j & 7;
    int lane = (j >> 3) & 63;
    int kc = j >> 9;                         // 0..1
    int o = lane & 15;
    int c = kc * 32 + (lane >> 4) * 8 + e;
    Wt5f[j] = f2b(w21[o * 64 + c]);
  }
}

// K1: streaming temporal conv (K=1/3/5/7 by channel quarter), x fp32 -> A bf16.
// Thread = one (b,c,hw4) column; float4 in, ush4 out; no LDS, no syncs.
__global__ __launch_bounds__(256, 8) void k1_tconv(
    const float* x, unsigned short* A,
    const float* w1, const float* w3, const float* w5, const float* w7) {
  int i = blockIdx.x * 256 + threadIdx.x;       // over 8*256*784 = 1,605,632
  int hw4 = i % 784;
  int bc = i / 784;
  int c = bc & 255;
  int b = bc >> 8;
  int q = c >> 6, cc = c & 63;
  float wf[7];
#pragma unroll
  for (int k = 0; k < 7; k++) wf[k] = 0.f;
  if (q == 0) { wf[3] = w1[cc]; }
  else if (q == 1) { wf[2] = w3[cc*3]; wf[3] = w3[cc*3+1]; wf[4] = w3[cc*3+2]; }
  else if (q == 2) { wf[1] = w5[cc*5]; wf[2] = w5[cc*5+1]; wf[3] = w5[cc*5+2]; wf[4] = w5[cc*5+3]; wf[5] = w5[cc*5+4]; }
  else { wf[0] = w7[cc*7]; wf[1] = w7[cc*7+1]; wf[2] = w7[cc*7+2]; wf[3] = w7[cc*7+3]; wf[4] = w7[cc*7+4]; wf[5] = w7[cc*7+5]; wf[6] = w7[cc*7+6]; }

  const float4* xp = (const float4*)x;
  size_t base = ((size_t)(b * 8) * 256 + c) * 784 + hw4;   // float4 units
  const int tstr = 256 * 784;
  float4 xv[8];
#pragma unroll
  for (int t = 0; t < 8; t++) xv[t] = xp[base + t * tstr];
#pragma unroll
  for (int t = 0; t < 8; t++) {
    float4 a = make_float4(0.f, 0.f, 0.f, 0.f);
#pragma unroll
    for (int d = -3; d <= 3; d++) {
      int ts = t + d;
      if (ts >= 0 && ts < 8) {
        float wvv = wf[d + 3];
        a.x = fmaf(wvv, xv[ts].x, a.x);
        a.y = fmaf(wvv, xv[ts].y, a.y);
        a.z = fmaf(wvv, xv[ts].z, a.z);
        a.w = fmaf(wvv, xv[ts].w, a.w);
      }
    }
    ush4 ov;
    ov.v[0] = f2b(a.x); ov.v[1] = f2b(a.y); ov.v[2] = f2b(a.z); ov.v[3] = f2b(a.w);
    *(ush4*)(A + (((size_t)(b * 8 + t) * 256 + c) * 3136 + hw4 * 4)) = ov;
  }
}

// K2: 1x1 conv 256->64 via MFMA + BN + ReLU -> R2t[n][hw][64] bf16,
//     + fused 1x1 conv 64->16 (MFMA) + BN + ReLU -> Yt fp32 [n][hw][16].
// Block = (n, 64 cols). sA staging with XOR swizzle (round-13-proven).
__global__ __launch_bounds__(256, 2) void k2_mfma(
    const unsigned short* A, unsigned short* R2t, float* Yt,
    const unsigned short* Wt1f, const unsigned short* Wt5f,
    const float* g, const float* bb, const float* g21, const float* b21) {
  __shared__ unsigned short sA[16384];          // 32 KB
  __shared__ unsigned short sOutT[64 * 70];     // 8,960 B
  int n = blockIdx.x / 49;
  int hw0 = (blockIdx.x % 49) * 64;
  const unsigned short* Ab = A + (size_t)n * 256 * 3136 + hw0;
  for (int idx = threadIdx.x; idx < 16384; idx += 256) {
    int c = idx >> 6, col = idx & 63;
    sA[(col * 256 + c) ^ ((col & 7) << 3)] = Ab[c * 3136 + col];
  }
  __syncthreads();
  int l = threadIdx.x & 63;
  int wv = threadIdx.x >> 6;                    // N-tile
  int l15 = l & 15, l4 = l >> 4;
  f32x4 acc[4];
#pragma unroll
  for (int m = 0; m < 4; m++) acc[m] = (f32x4){0.f, 0.f, 0.f, 0.f};
#pragma unroll
  for (int kc = 0; kc < 8; kc++) {
    int colt = wv * 16 + l15;
    int us = (colt * 256 + kc * 32 + (l4 << 3)) ^ ((colt & 7) << 3);
    bf16x8 b = *(const bf16x8*)(sA + us);
#pragma unroll
    for (int m = 0; m < 4; m++) {
      bf16x8 a = *(const bf16x8*)(Wt1f + (((kc * 4 + m) * 64 + l) << 3));
      acc[m] = __builtin_amdgcn_mfma_f32_16x16x32_bf16(a, b, acc[m], 0, 0, 0);
    }
  }
  // BN + ReLU into sOutT [col][o pad70]
  int colw = wv * 16 + l15;
#pragma unroll
  for (int m = 0; m < 4; m++) {
#pragma unroll
    for (int r = 0; r < 4; r++) {
      int o = m * 16 + l4 * 4 + r;
      float v = fmaxf(fmaf(acc[m][r], g[o] * MSC_BNI, bb[o]), 0.f);
      sOutT[colw * 70 + o] = f2b(v);
    }
  }
  __syncthreads();
  // R2t coalesced stores: 512 chunks of 16B
#pragma unroll
  for (int k = 0; k < 2; k++) {
    int ch = threadIdx.x + k * 256;
    int col = ch >> 3, gg = ch & 7;
    bf16x8 v = *(const bf16x8*)(sOutT + col * 70 + gg * 8);
    *(bf16x8*)(R2t + ((size_t)n * 3136 + hw0 + col) * 64 + gg * 8) = v;
  }
  // fused k3: Y = relu(bn21(W21 . R2)) for this wave's 16 cols.
  f32x4 a5 = (f32x4){0.f, 0.f, 0.f, 0.f};
#pragma unroll
  for (int kc = 0; kc < 2; kc++) {
    bf16x8 bfr = *(const bf16x8*)(sOutT + colw * 70 + kc * 32 + l4 * 8);
    bf16x8 a = *(const bf16x8*)(Wt5f + ((kc * 64 + l) << 3));
    a5 = __builtin_amdgcn_mfma_f32_16x16x32_bf16(a, bfr, a5, 0, 0, 0);
  }
  int o0 = l4 * 4;
  float4 yv;
  yv.x = fmaxf(fmaf(a5[0], g21[o0+0] * MSC_BNI, b21[o0+0]), 0.f);
  yv.y = fmaxf(fmaf(a5[1], g21[o0+1] * MSC_BNI, b21[o0+1]), 0.f);
  yv.z = fmaxf(fmaf(a5[2], g21[o0+2] * MSC_BNI, b21[o0+2]), 0.f);
  yv.w = fmaxf(fmaf(a5[3], g21[o0+3] * MSC_BNI, b21[o0+3]), 0.f);
  *(float4*)(Yt + ((size_t)n * 3136 + hw0 + colw) * 16 + o0) = yv;
}

// K4: 7x7-displacement correlation /16 + BN + ReLU -> COt[n][hw][64] bf16.
__global__ __launch_bounds__(256, 3) void k4_corr(
    const float* Yt, unsigned short* COt, const float* g, const float* bb) {
  __shared__ float sb[10 * 62 * 20];            // [r][cl][c pad20], 49,600 B
  int n = blockIdx.x / 14;
  int h0 = (blockIdx.x % 14) * 4;
  int t = n & 7;
  int n2 = (t < 7) ? n + 1 : n;
  const float* Yb = Yt + (size_t)n2 * 3136 * 16;
  for (int idx = threadIdx.x; idx < 2480; idx += 256) {
    int c4 = idx & 3;
    int pix = idx >> 2;                         // r*62 + cl
    int r = pix / 62, cl = pix - r * 62;
    int gr = h0 - 3 + r, gc = cl - 3;
    float4 v = make_float4(0.f, 0.f, 0.f, 0.f);
    if (gr >= 0 && gr < 56 && gc >= 0 && gc < 56)
      v = *(const float4*)(Yb + (gr * 56 + gc) * 16 + c4 * 4);
    *(float4*)&sb[(r * 62 + cl) * 20 + c4 * 4] = v;
  }
  __syncthreads();
  int pos = threadIdx.x;
  if (pos < 224) {
    int hl = pos / 56, wcol = pos - (pos / 56) * 56;
    const float* Ya = Yt + ((size_t)n * 3136 + (h0 + hl) * 56 + wcol) * 16;
    float4 a0 = *(const float4*)(Ya + 0);
    float4 a1 = *(const float4*)(Ya + 4);
    float4 a2 = *(const float4*)(Ya + 8);
    float4 a3 = *(const float4*)(Ya + 12);
    float corr[49];
    for (int di = 0; di < 7; di++) {
      for (int dj = 0; dj < 7; dj++) {
        const float* sp = &sb[((hl + di) * 62 + wcol + dj) * 20];
        float4 b0 = *(const float4*)(sp + 0);
        float4 b1 = *(const float4*)(sp + 4);
        float4 b2 = *(const float4*)(sp + 8);
        float4 b3 = *(const float4*)(sp + 12);
        float s = 0.f;
        s = fmaf(a0.x, b0.x, s); s = fmaf(a0.y, b0.y, s);
        s = fmaf(a0.z, b0.z, s); s = fmaf(a0.w, b0.w, s);
        s = fmaf(a1.x, b1.x, s); s = fmaf(a1.y, b1.y, s);
        s = fmaf(a1.z, b1.z, s); s = fmaf(a1.w, b1.w, s);
        s = fmaf(a2.x, b2.x, s); s = fmaf(a2.y, b2.y, s);
        s = fmaf(a2.z, b2.z, s); s = fmaf(a2.w, b2.w, s);
        s = fmaf(a3.x, b3.x, s); s = fmaf(a3.y, b3.y, s);
        s = fmaf(a3.z, b3.z, s); s = fmaf(a3.w, b3.w, s);
        int k = di * 7 + dj;
        corr[k] = fmaxf(fmaf(s * 0.0625f, g[k] * MSC_BNI, bb[k]), 0.f);
      }
    }
    unsigned short* Cp = COt + ((size_t)n * 3136 + (h0 + hl) * 56 + wcol) * 64;
#pragma unroll
    for (int gq = 0; gq < 8; gq++) {
      bf16x8 pv;
#pragma unroll
      for (int j = 0; j < 8; j++) {
        int k = gq * 8 + j;
        pv[j] = (k < 49) ? (short)f2b(corr[k]) : (short)0;
      }
      *(bf16x8*)(Cp + gq * 8) = pv;
    }
  }
}

// K56: FUSED 3x3 conv (MFMA implicit GEMM) + BN + ReLU
//      + [1x1 conv 49->64 + BN + R2-residual + ReLU] recomputed in epilogue.
__global__ __launch_bounds__(256, 3) void k56_mfma(
    const unsigned short* R2t, const unsigned short* COt, unsigned short* C2t,
    const unsigned short* Wt2f, const unsigned short* Wt4f,
    const float* g2, const float* b2, const float* g23, const float* b23) {
  __shared__ unsigned short sIn[22272];         // 6*58*64, 44,544 B
  int n = blockIdx.x / 14;
  int h0 = (blockIdx.x % 14) * 4;
  const unsigned short* Rt = R2t + (size_t)n * 3136 * 64;
  for (int ch = threadIdx.x; ch < 2784; ch += 256) {
    int rc = ch >> 3;                           // row*58 + col
    int cg = ch & 7;
    int row = rc / 58, col = rc - row * 58;
    int gr = h0 - 1 + row, gc = col - 1;
    bf16x8 v = (bf16x8){0, 0, 0, 0, 0, 0, 0, 0};
    if (gr >= 0 && gr < 56 && gc >= 0 && gc < 56)
      v = *(const bf16x8*)(Rt + (gr * 56 + gc) * 64 + cg * 8);
    *(bf16x8*)(sIn + rc * 64 + ((cg ^ (col & 7)) << 3)) = v;
  }
  __syncthreads();
  int l = threadIdx.x & 63;
  int wv = threadIdx.x >> 6;                    // 0..3
  int l15 = l & 15, l4 = l >> 4;
  f32x4 acc[4][4];
#pragma unroll
  for (int m = 0; m < 4; m++)
#pragma unroll
    for (int t = 0; t < 4; t++) acc[m][t] = (f32x4){0.f, 0.f, 0.f, 0.f};

  for (int tap = 0; tap < 9; tap++) {
    int ky = tap / 3;
    int kx = tap - ky * 3;
    for (int kc = 0; kc < 2; kc++) {
      bf16x8 a[4];
#pragma unroll
      for (int m = 0; m < 4; m++)
        a[m] = *(const bf16x8*)(Wt2f + ((((tap * 2 + kc) * 4 + m) * 64 + l) << 3));
#pragma unroll
      for (int t = 0; t < 4; t++) {
        int ct = wv * 4 + t;
        int rowt = ct >> 2, col0 = (ct & 3) << 4;
        int lcol = col0 + l15 + kx;
        if (lcol > 57) lcol = 57;               // discarded cols read padding
        int us = ((((rowt + ky) * 58 + lcol) * 64) + kc * 32 + (l4 << 3))
                 ^ ((lcol & 7) << 3);
        bf16x8 b = *(const bf16x8*)(sIn + us);
#pragma unroll
        for (int m = 0; m < 4; m++)
          acc[m][t] = __builtin_amdgcn_mfma_f32_16x16x32_bf16(a[m], b, acc[m][t], 0, 0, 0);
      }
    }
  }

#pragma unroll
  for (int t = 0; t < 4; t++) {
    int ct = wv * 4 + t;
    int rowt = ct >> 2, col0 = (ct & 3) << 4;
    int cc = col0 + l15;
    int cc_cl = (cc < 56) ? cc : 55;
    int gbase = ((int)(n * 3136) + (h0 + rowt) * 56 + cc_cl) * 64;
    // k5 GEMM (exec-uniform, clamped addresses for discarded lanes)
    f32x4 acc2[4];
#pragma unroll
    for (int m = 0; m < 4; m++) acc2[m] = (f32x4){0.f, 0.f, 0.f, 0.f};
#pragma unroll
    for (int kc = 0; kc < 2; kc++) {
      bf16x8 bco = *(const bf16x8*)(COt + gbase + kc * 32 + l4 * 8);
#pragma unroll
      for (int m = 0; m < 4; m++) {
        bf16x8 a = *(const bf16x8*)(Wt4f + (((kc * 4 + m) * 64 + l) << 3));
        acc2[m] = __builtin_amdgcn_mfma_f32_16x16x32_bf16(a, bco, acc2[m], 0, 0, 0);
      }
    }
    if (cc < 56) {
      int rc = (rowt + 1) * 58 + cc + 1;        // center cell in sIn
#pragma unroll
      for (int m = 0; m < 4; m++) {
        int cg0 = 2 * m + (l4 >> 1);
        int us = rc * 64 + ((cg0 ^ ((cc + 1) & 7)) << 3) + (l4 & 1) * 4;
        ush4 rv = *(const ush4*)(sIn + us);
        ush4 ov;
#pragma unroll
        for (int r = 0; r < 4; r++) {
          int o = m * 16 + l4 * 4 + r;
          float o2 = fmaxf(fmaf(acc2[m][r], g23[o] * MSC_BNI, b23[o]) + b2f(rv.v[r]), 0.f);
          float v = fmaxf(fmaf(acc[m][t][r], g2[o] * MSC_BNI, b2[o]), 0.f) + o2;
          ov.v[r] = f2b(v);
        }
        *(ush4*)(C2t + gbase + m * 16 + l4 * 4) = ov;
      }
    }
  }
}

// K7: 1x1 conv 64->256 via MFMA GEMM + BN + x-residual + ReLU -> d_out fp32.
__global__ __launch_bounds__(256, 3) void k7_mfma(
    const unsigned short* C2t, const float* x, float* outp,
    const unsigned short* Wt3f, const float* g, const float* bb) {
  __shared__ float sOut[64 * 68];               // 17,408 B
  int n = blockIdx.x / 49;
  int hw0 = (blockIdx.x % 49) * 64;
  int l = threadIdx.x & 63;
  int wv = threadIdx.x >> 6;                    // 0..3
  int l15 = l & 15, l4 = l >> 4;
  f32x4 acc[4][4];
#pragma unroll
  for (int m = 0; m < 4; m++)
#pragma unroll
    for (int t = 0; t < 4; t++) acc[m][t] = (f32x4){0.f, 0.f, 0.f, 0.f};

#pragma unroll
  for (int kc = 0; kc < 2; kc++) {
    bf16x8 a[4];
#pragma unroll
    for (int m = 0; m < 4; m++)
      a[m] = *(const bf16x8*)(Wt3f + (((kc * 16 + wv * 4 + m) * 64 + l) << 3));
#pragma unroll
    for (int t = 0; t < 4; t++) {
      int colt = t * 16 + l15;
      bf16x8 b = *(const bf16x8*)(C2t + ((size_t)n * 3136 + hw0 + colt) * 64 + kc * 32 + l4 * 8);
#pragma unroll
      for (int m = 0; m < 4; m++)
        acc[m][t] = __builtin_amdgcn_mfma_f32_16x16x32_bf16(a[m], b, acc[m][t], 0, 0, 0);
    }
  }

  // epilogue: 4 passes; pass m covers o = wv*64 + m*16 + [0,16) for wv 0..3.
  for (int m = 0; m < 4; m++) {
#pragma unroll
    for (int t = 0; t < 4; t++)
#pragma unroll
      for (int r = 0; r < 4; r++)
        sOut[(wv * 16 + l4 * 4 + r) * 68 + t * 16 + l15] = acc[m][t][r];
    __syncthreads();
#pragma unroll
    for (int s = 0; s < 4; s++) {
      int ro = (threadIdx.x >> 4) + s * 16;     // 0..63
      int o = (ro >> 4) * 64 + m * 16 + (ro & 15);
      int colq = (threadIdx.x & 15) * 4;
      float4 v = *(float4*)&sOut[ro * 68 + colq];
      int off = (n * 256 + o) * 3136 + hw0 + colq;
      float4 xv = *(const float4*)(x + off);
      float sg = g[o] * MSC_BNI, bo = bb[o];
      float4 ov;
      ov.x = fmaxf(fmaf(v.x, sg, bo) + xv.x, 0.f);
      ov.y = fmaxf(fmaf(v.y, sg, bo) + xv.y, 0.f);
      ov.z = fmaxf(fmaf(v.z, sg, bo) + xv.z, 0.f);
      ov.w = fmaxf(fmaf(v.w, sg, bo) + xv.w, 0.f);
      *(float4*)(outp + off) = ov;
    }
    __syncthreads();
  }
}

extern "C" void kernel_launch(void* const* d_in, const int* in_sizes, int n_in,
                              void* d_out, int out_size, void* d_ws, size_t ws_size,
                              hipStream_t stream) {
  const float* x        = (const float*)d_in[0];
  const float* w1       = (const float*)d_in[1];
  const float* w3       = (const float*)d_in[2];
  const float* w5       = (const float*)d_in[3];
  const float* w7       = (const float*)d_in[4];
  const float* w_conv1  = (const float*)d_in[5];
  const float* g1       = (const float*)d_in[6];
  const float* b1       = (const float*)d_in[7];
  const float* w_conv21 = (const float*)d_in[8];
  const float* g21      = (const float*)d_in[9];
  const float* b21      = (const float*)d_in[10];
  const float* g22      = (const float*)d_in[11];
  const float* b22      = (const float*)d_in[12];
  const float* w_conv22 = (const float*)d_in[13];
  const float* g23      = (const float*)d_in[14];
  const float* b23      = (const float*)d_in[15];
  const float* w_conv2  = (const float*)d_in[16];
  const float* g2       = (const float*)d_in[17];
  const float* b2       = (const float*)d_in[18];
  const float* w_conv3  = (const float*)d_in[19];
  const float* g3       = (const float*)d_in[20];
  const float* b3       = (const float*)d_in[21];

  // d_out (fp32, 205,520,896 B) scratch map (all dead before K7's rewrite):
  //   Yt   fp32 [0 .. 12,845,056)             K2 w, K4 r   [n][hw][16]
  //   A    bf16 [12,845,056 .. 115,605,504)   K1 w, K2 r   [n][c][hw] (dead after K2)
  //   COt  bf16 [12,845,056 .. 38,535,168)    K4 w, K56 r  [n][hw][64] (A dead)
  //   R2t  bf16 [115,605,504 .. 141,295,616)  K2 w; K56 r  [n][hw][64]
  //   Wt2f bf16 [141,295,616 .. +73,728)      K0 w, K56 r
  //   Wt1f bf16 [141,369,344 .. +32,768)      K0 w, K2 r
  //   Wt4f bf16 [141,402,112 .. +8,192)       K0 w, K56 r
  //   Wt5f bf16 [141,410,304 .. +2,048)       K0 w, K2 r
  // d_ws:
  //   C2t  bf16 [0 .. 25,690,112)             K56 w, K7 r  [n][hw][64]
  //   Wt3f bf16 [25,690,112 .. +32,768)       K0 w, K7 r (K7 overwrites d_out)
  char* ob = (char*)d_out;
  char* ws = (char*)d_ws;
  float*          Yt   = (float*)ob;
  unsigned short* A    = (unsigned short*)(ob + 12845056);
  unsigned short* COt  = (unsigned short*)(ob + 12845056);
  unsigned short* R2t  = (unsigned short*)(ob + 115605504);
  unsigned short* Wt2f = (unsigned short*)(ob + 141295616);
  unsigned short* Wt1f = (unsigned short*)(ob + 141369344);
  unsigned short* Wt4f = (unsigned short*)(ob + 141402112);
  unsigned short* Wt5f = (unsigned short*)(ob + 141410304);
  unsigned short* C2t  = (unsigned short*)ws;
  unsigned short* Wt3f = (unsigned short*)(ws + 25690112);

  k0_prep <<<dim3(292),     dim3(256), 0, stream>>>(w_conv1, w_conv2, w_conv3, w_conv22,
                                                    w_conv21, Wt1f, Wt2f, Wt3f, Wt4f, Wt5f);
  k1_tconv<<<dim3(6272),    dim3(256), 0, stream>>>(x, A, w1, w3, w5, w7);
  k2_mfma <<<dim3(64 * 49), dim3(256), 0, stream>>>(A, R2t, Yt, Wt1f, Wt5f,
                                                    g1, b1, g21, b21);
  k4_corr <<<dim3(64 * 14), dim3(256), 0, stream>>>(Yt, COt, g22, b22);
  k56_mfma<<<dim3(64 * 14), dim3(256), 0, stream>>>(R2t, COt, C2t, Wt2f, Wt4f, g2, b2, g23, b23);
  k7_mfma <<<dim3(64 * 49), dim3(256), 0, stream>>>(C2t, x, (float*)d_out, Wt3f, g3, b3);
}

// Round 23
// 228.487 us; speedup vs baseline: 1.1514x; 1.1514x over previous
//
#include <hip/hip_runtime.h>

// MsCorrBlock: B=8 T=8 C=256 PL=64 CR=16 H=W=56 HW=3136 NT=64 PS=7 KK=49
// Output dtype: FLOAT32 (205,520,896 B). BNI = 1/sqrt(1+1e-5).

#define MSC_BNI 0.9999950000374997f

typedef __attribute__((ext_vector_type(8))) short bf16x8;
typedef __attribute__((ext_vector_type(4))) float f32x4;
struct __align__(8) ush4 { unsigned short v[4]; };

static __device__ __forceinline__ float b2f(unsigned short h) {
  return __uint_as_float(((unsigned int)h) << 16);
}
static __device__ __forceinline__ unsigned short f2b(float f) {
  unsigned int u = __float_as_uint(f);
  u = u + 0x7FFFu + ((u >> 16) & 1u);   // round to nearest even
  return (unsigned short)(u >> 16);
}

// K0: pack bf16 MFMA A-fragments (convention validated rounds 11-21):
//   Wt2f [tap9][kc2][m4][lane64][e8]: w2[o=m*16+(l&15)][c=kc*32+(l>>4)*8+e][tap]
//   Wt3f [kc2][m16][lane64][e8]:      w3[o][c]
//   Wt1f [kc8][m4][lane64][e8]:       w1[o][c]
//   Wt4f [kc2][m4][lane64][e8]:      w22[o][c] (c>=49 -> 0)
//   Wt5f [kc2][lane64][e8]:          w21[o=l&15][c=kc*32+(l>>4)*8+e]  (M=16)
__global__ __launch_bounds__(256) void k0_prep(
    const float* w1, const float* w2, const float* w3, const float* w22,
    const float* w21,
    unsigned short* Wt1f, unsigned short* Wt2f, unsigned short* Wt3f,
    unsigned short* Wt4f, unsigned short* Wt5f) {
  int idx = blockIdx.x * 256 + threadIdx.x;
  if (idx < 36864) {
    int j = idx;
    int e = j & 7;
    int lane = (j >> 3) & 63;
    int m = (j >> 9) & 3;
    int kc = (j >> 11) & 1;
    int tap = j >> 12;                       // 0..8
    int o = m * 16 + (lane & 15);
    int c = kc * 32 + (lane >> 4) * 8 + e;
    Wt2f[j] = f2b(w2[(o * 64 + c) * 9 + tap]);
  } else if (idx < 36864 + 16384) {
    int j = idx - 36864;
    int e = j & 7;
    int lane = (j >> 3) & 63;
    int m = (j >> 9) & 15;
    int kc = j >> 13;                        // 0..1
    int o = m * 16 + (lane & 15);
    int c = kc * 32 + (lane >> 4) * 8 + e;
    Wt3f[j] = f2b(w3[o * 64 + c]);
  } else if (idx < 36864 + 16384 + 16384) {
    int j = idx - 36864 - 16384;
    int e = j & 7;
    int lane = (j >> 3) & 63;
    int m = (j >> 9) & 3;
    int kc = j >> 11;                        // 0..7
    int o = m * 16 + (lane & 15);
    int c = kc * 32 + (lane >> 4) * 8 + e;
    Wt1f[j] = f2b(w1[o * 256 + c]);
  } else if (idx < 36864 + 16384 + 16384 + 4096) {
    int j = idx - 36864 - 16384 - 16384;
    int e = j & 7;
    int lane = (j >> 3) & 63;
    int m = (j >> 9) & 3;
    int kc = j >> 11;                        // 0..1
    int o = m * 16 + (lane & 15);
    int c = kc * 32 + (lane >> 4) * 8 + e;
    Wt4f[j] = (c < 49) ? f2b(w22[o * 49 + c]) : (unsigned short)0;
  } else if (idx < 36864 + 16384 + 16384 + 4096 + 1024) {
    int j = idx - 36864 - 16384 - 16384 - 4096;
    int e = j & 7;
    int lane = (j >> 3) & 63;
    int kc = j >> 9;                         // 0..1
    int o = lane & 15;
    int c = kc * 32 + (lane >> 4) * 8 + e;
    Wt5f[j] = f2b(w21[o * 64 + c]);
  }
}

// K12: FUSED temporal conv + 1x1 conv 256->64 (MFMA) + BN + ReLU -> R2t bf16,
//      + 1x1 conv 64->16 (MFMA) + BN + ReLU -> Yt fp32 [n][hw][16].
// (256,2): full register budget. Register-level double-buffer xnA/xnB: loads
// for chunk k+2 issued at iter k, consumed at iter k+1 (full-iter distance).
__global__ __launch_bounds__(256, 2) void k12_fused(
    const float* x, unsigned short* R2t, float* Yt,
    const unsigned short* Wt1f, const unsigned short* Wt5f,
    const float* w1, const float* w3, const float* w5, const float* w7,
    const float* g, const float* bb, const float* g21, const float* b21) {
  __shared__ unsigned short lds[17408];         // dbuf 2 x 8704; sOutT reuse
  int b = blockIdx.x / 98;
  int hw0 = (blockIdx.x % 98) * 32;
  int tid = threadIdx.x;
  int l = tid & 63, wv = tid >> 6;
  int l15 = l & 15, l4 = l >> 4;
  int colp = tid & 31;
  int cbase = tid >> 5;                         // 0..7
  const int tstr = 256 * 3136;

  f32x4 acc[2][4][2];
#pragma unroll
  for (int tt = 0; tt < 2; tt++)
#pragma unroll
    for (int m = 0; m < 4; m++)
#pragma unroll
      for (int nt = 0; nt < 2; nt++) acc[tt][m][nt] = (f32x4){0.f, 0.f, 0.f, 0.f};

  float xnA[4][8], xnB[4][8], wfc[4][7];

  auto loadx = [&](int kn, float xv[4][8]) {
#pragma unroll
    for (int p = 0; p < 4; p++) {
      int c = cbase + p * 8;
      const float* xb = x + ((size_t)(b * 8) * 256 + kn * 32 + c) * 3136 + hw0 + colp;
#pragma unroll
      for (int t = 0; t < 8; t++) xv[p][t] = xb[t * tstr];
    }
  };
  auto loadwf = [&](int kn) {
    int qn = kn >> 1;
#pragma unroll
    for (int p = 0; p < 4; p++) {
      int c = cbase + p * 8;
      int cq = (kn & 1) * 32 + c;
#pragma unroll
      for (int k = 0; k < 7; k++) wfc[p][k] = 0.f;
      if (qn == 0) { wfc[p][3] = w1[cq]; }
      else if (qn == 1) { wfc[p][2] = w3[cq*3]; wfc[p][3] = w3[cq*3+1]; wfc[p][4] = w3[cq*3+2]; }
      else if (qn == 2) { wfc[p][1] = w5[cq*5]; wfc[p][2] = w5[cq*5+1]; wfc[p][3] = w5[cq*5+2]; wfc[p][4] = w5[cq*5+3]; wfc[p][5] = w5[cq*5+4]; }
      else { wfc[p][0] = w7[cq*7]; wfc[p][1] = w7[cq*7+1]; wfc[p][2] = w7[cq*7+2]; wfc[p][3] = w7[cq*7+3]; wfc[p][4] = w7[cq*7+4]; wfc[p][5] = w7[cq*7+5]; wfc[p][6] = w7[cq*7+6]; }
    }
  };
  auto tconv = [&](const float xv[4][8], unsigned short* buf) {
#pragma unroll
    for (int p = 0; p < 4; p++) {
      int c = cbase + p * 8;
#pragma unroll
      for (int t = 0; t < 8; t++) {
        float a = 0.f;
#pragma unroll
        for (int d = -3; d <= 3; d++) {
          int ts = t + d;
          if (ts >= 0 && ts < 8) a = fmaf(wfc[p][d + 3], xv[p][ts], a);
        }
        buf[(t * 32 + colp) * 34 + c] = f2b(a);
      }
    }
  };
  auto mfma_step = [&](const unsigned short* buf, int kc8) {
#pragma unroll
    for (int tt = 0; tt < 2; tt++) {
      int t = wv * 2 + tt;
#pragma unroll
      for (int nt = 0; nt < 2; nt++) {
        int colt = nt * 16 + l15;
        bf16x8 bfr = *(const bf16x8*)(buf + (t * 32 + colt) * 34 + l4 * 8);
#pragma unroll
        for (int m = 0; m < 4; m++) {
          bf16x8 a = *(const bf16x8*)(Wt1f + (((kc8 * 4 + m) * 64 + l) << 3));
          acc[tt][m][nt] = __builtin_amdgcn_mfma_f32_16x16x32_bf16(a, bfr, acc[tt][m][nt], 0, 0, 0);
        }
      }
    }
  };

  // prologue: chunk0 + chunk1 loads in flight, tconv chunk0 -> buf0
  loadx(0, xnA);
  loadx(1, xnB);
  loadwf(0);
  tconv(xnA, lds);

#pragma unroll
  for (int kk = 0; kk < 8; kk += 2) {
    __syncthreads();                            // buf0(kk) visible; buf1 reads done
    if (kk + 2 < 8) loadx(kk + 2, xnA);         // issue early: consumed next iter
    mfma_step(lds, kk);
    loadwf(kk + 1);
    tconv(xnB, lds + 8704);                     // chunk kk+1 -> buf1
    __syncthreads();                            // buf1(kk+1) visible; buf0 reads done
    if (kk + 3 < 8) loadx(kk + 3, xnB);
    mfma_step(lds + 8704, kk + 1);
    if (kk + 2 < 8) { loadwf(kk + 2); tconv(xnA, lds); }
  }
  __syncthreads();                              // all MFMA reads done; reuse lds
  // epilogue per tt: sOutT = lds holds [tb4][col32][o pad70] bf16 R2.
  unsigned short* sOutT = lds;
  for (int tt = 0; tt < 2; tt++) {
#pragma unroll
    for (int m = 0; m < 4; m++)
#pragma unroll
      for (int nt = 0; nt < 2; nt++) {
        int col = nt * 16 + l15;
#pragma unroll
        for (int r = 0; r < 4; r++) {
          int o = m * 16 + l4 * 4 + r;
          float v = fmaxf(fmaf(acc[tt][m][nt][r], g[o] * MSC_BNI, bb[o]), 0.f);
          sOutT[(wv * 32 + col) * 70 + o] = f2b(v);
        }
      }
    __syncthreads();
    // R2t coalesced stores
#pragma unroll
    for (int k = 0; k < 4; k++) {
      int ch = tid + k * 256;                   // 1024 chunks of 16B
      int tb = ch >> 8, col = (ch >> 3) & 31, gg = ch & 7;
      int t = tb * 2 + tt;
      bf16x8 v = *(const bf16x8*)(sOutT + (tb * 32 + col) * 70 + gg * 8);
      *(bf16x8*)(R2t + (((size_t)(b * 8 + t) * 3136) + hw0 + col) * 64 + gg * 8) = v;
    }
    // fused k3: Y = relu(bn21(W21 . R2)), wave wv handles its own t-frame.
    {
      int t = wv * 2 + tt;
#pragma unroll
      for (int ct2 = 0; ct2 < 2; ct2++) {
        f32x4 a5 = (f32x4){0.f, 0.f, 0.f, 0.f};
#pragma unroll
        for (int kc = 0; kc < 2; kc++) {
          bf16x8 bfr = *(const bf16x8*)(sOutT + (wv * 32 + ct2 * 16 + l15) * 70 + kc * 32 + l4 * 8);
          bf16x8 a = *(const bf16x8*)(Wt5f + ((kc * 64 + l) << 3));
          a5 = __builtin_amdgcn_mfma_f32_16x16x32_bf16(a, bfr, a5, 0, 0, 0);
        }
        int hw = hw0 + ct2 * 16 + l15;
        float4 yv;
        {
          int o0 = l4 * 4;
          yv.x = fmaxf(fmaf(a5[0], g21[o0+0] * MSC_BNI, b21[o0+0]), 0.f);
          yv.y = fmaxf(fmaf(a5[1], g21[o0+1] * MSC_BNI, b21[o0+1]), 0.f);
          yv.z = fmaxf(fmaf(a5[2], g21[o0+2] * MSC_BNI, b21[o0+2]), 0.f);
          yv.w = fmaxf(fmaf(a5[3], g21[o0+3] * MSC_BNI, b21[o0+3]), 0.f);
        }
        *(float4*)(Yt + (((size_t)(b * 8 + t) * 3136) + hw) * 16 + l4 * 4) = yv;
      }
    }
    __syncthreads();
  }
}

// K4: 7x7-displacement correlation /16 + BN + ReLU -> COt[n][hw][64] bf16.
__global__ __launch_bounds__(256, 3) void k4_corr(
    const float* Yt, unsigned short* COt, const float* g, const float* bb) {
  __shared__ float sb[10 * 62 * 20];            // [r][cl][c pad20], 49,600 B
  int n = blockIdx.x / 14;
  int h0 = (blockIdx.x % 14) * 4;
  int t = n & 7;
  int n2 = (t < 7) ? n + 1 : n;
  const float* Yb = Yt + (size_t)n2 * 3136 * 16;
  for (int idx = threadIdx.x; idx < 2480; idx += 256) {
    int c4 = idx & 3;
    int pix = idx >> 2;                         // r*62 + cl
    int r = pix / 62, cl = pix - r * 62;
    int gr = h0 - 3 + r, gc = cl - 3;
    float4 v = make_float4(0.f, 0.f, 0.f, 0.f);
    if (gr >= 0 && gr < 56 && gc >= 0 && gc < 56)
      v = *(const float4*)(Yb + (gr * 56 + gc) * 16 + c4 * 4);
    *(float4*)&sb[(r * 62 + cl) * 20 + c4 * 4] = v;
  }
  __syncthreads();
  int pos = threadIdx.x;
  if (pos < 224) {
    int hl = pos / 56, wcol = pos - (pos / 56) * 56;
    const float* Ya = Yt + ((size_t)n * 3136 + (h0 + hl) * 56 + wcol) * 16;
    float4 a0 = *(const float4*)(Ya + 0);
    float4 a1 = *(const float4*)(Ya + 4);
    float4 a2 = *(const float4*)(Ya + 8);
    float4 a3 = *(const float4*)(Ya + 12);
    float corr[49];
    for (int di = 0; di < 7; di++) {
      for (int dj = 0; dj < 7; dj++) {
        const float* sp = &sb[((hl + di) * 62 + wcol + dj) * 20];
        float4 b0 = *(const float4*)(sp + 0);
        float4 b1 = *(const float4*)(sp + 4);
        float4 b2 = *(const float4*)(sp + 8);
        float4 b3 = *(const float4*)(sp + 12);
        float s = 0.f;
        s = fmaf(a0.x, b0.x, s); s = fmaf(a0.y, b0.y, s);
        s = fmaf(a0.z, b0.z, s); s = fmaf(a0.w, b0.w, s);
        s = fmaf(a1.x, b1.x, s); s = fmaf(a1.y, b1.y, s);
        s = fmaf(a1.z, b1.z, s); s = fmaf(a1.w, b1.w, s);
        s = fmaf(a2.x, b2.x, s); s = fmaf(a2.y, b2.y, s);
        s = fmaf(a2.z, b2.z, s); s = fmaf(a2.w, b2.w, s);
        s = fmaf(a3.x, b3.x, s); s = fmaf(a3.y, b3.y, s);
        s = fmaf(a3.z, b3.z, s); s = fmaf(a3.w, b3.w, s);
        int k = di * 7 + dj;
        corr[k] = fmaxf(fmaf(s * 0.0625f, g[k] * MSC_BNI, bb[k]), 0.f);
      }
    }
    unsigned short* Cp = COt + ((size_t)n * 3136 + (h0 + hl) * 56 + wcol) * 64;
#pragma unroll
    for (int gq = 0; gq < 8; gq++) {
      bf16x8 pv;
#pragma unroll
      for (int j = 0; j < 8; j++) {
        int k = gq * 8 + j;
        pv[j] = (k < 49) ? (short)f2b(corr[k]) : (short)0;
      }
      *(bf16x8*)(Cp + gq * 8) = pv;
    }
  }
}

// K56: FUSED 3x3 conv (MFMA implicit GEMM) + BN + ReLU
//      + [1x1 conv 49->64 + BN + R2-residual + ReLU] recomputed in epilogue.
__global__ __launch_bounds__(256, 3) void k56_mfma(
    const unsigned short* R2t, const unsigned short* COt, unsigned short* C2t,
    const unsigned short* Wt2f, const unsigned short* Wt4f,
    const float* g2, const float* b2, const float* g23, const float* b23) {
  __shared__ unsigned short sIn[22272];         // 6*58*64, 44,544 B
  int n = blockIdx.x / 14;
  int h0 = (blockIdx.x % 14) * 4;
  const unsigned short* Rt = R2t + (size_t)n * 3136 * 64;
  for (int ch = threadIdx.x; ch < 2784; ch += 256) {
    int rc = ch >> 3;                           // row*58 + col
    int cg = ch & 7;
    int row = rc / 58, col = rc - row * 58;
    int gr = h0 - 1 + row, gc = col - 1;
    bf16x8 v = (bf16x8){0, 0, 0, 0, 0, 0, 0, 0};
    if (gr >= 0 && gr < 56 && gc >= 0 && gc < 56)
      v = *(const bf16x8*)(Rt + (gr * 56 + gc) * 64 + cg * 8);
    *(bf16x8*)(sIn + rc * 64 + ((cg ^ (col & 7)) << 3)) = v;
  }
  __syncthreads();
  int l = threadIdx.x & 63;
  int wv = threadIdx.x >> 6;                    // 0..3
  int l15 = l & 15, l4 = l >> 4;
  f32x4 acc[4][4];
#pragma unroll
  for (int m = 0; m < 4; m++)
#pragma unroll
    for (int t = 0; t < 4; t++) acc[m][t] = (f32x4){0.f, 0.f, 0.f, 0.f};

  for (int tap = 0; tap < 9; tap++) {
    int ky = tap / 3;
    int kx = tap - ky * 3;
    for (int kc = 0; kc < 2; kc++) {
      bf16x8 a[4];
#pragma unroll
      for (int m = 0; m < 4; m++)
        a[m] = *(const bf16x8*)(Wt2f + ((((tap * 2 + kc) * 4 + m) * 64 + l) << 3));
#pragma unroll
      for (int t = 0; t < 4; t++) {
        int ct = wv * 4 + t;
        int rowt = ct >> 2, col0 = (ct & 3) << 4;
        int lcol = col0 + l15 + kx;
        if (lcol > 57) lcol = 57;               // discarded cols read padding
        int us = ((((rowt + ky) * 58 + lcol) * 64) + kc * 32 + (l4 << 3))
                 ^ ((lcol & 7) << 3);
        bf16x8 b = *(const bf16x8*)(sIn + us);
#pragma unroll
        for (int m = 0; m < 4; m++)
          acc[m][t] = __builtin_amdgcn_mfma_f32_16x16x32_bf16(a[m], b, acc[m][t], 0, 0, 0);
      }
    }
  }

#pragma unroll
  for (int t = 0; t < 4; t++) {
    int ct = wv * 4 + t;
    int rowt = ct >> 2, col0 = (ct & 3) << 4;
    int cc = col0 + l15;
    int cc_cl = (cc < 56) ? cc : 55;
    int gbase = ((int)(n * 3136) + (h0 + rowt) * 56 + cc_cl) * 64;
    // k5 GEMM (exec-uniform, clamped addresses for discarded lanes)
    f32x4 acc2[4];
#pragma unroll
    for (int m = 0; m < 4; m++) acc2[m] = (f32x4){0.f, 0.f, 0.f, 0.f};
#pragma unroll
    for (int kc = 0; kc < 2; kc++) {
      bf16x8 bco = *(const bf16x8*)(COt + gbase + kc * 32 + l4 * 8);
#pragma unroll
      for (int m = 0; m < 4; m++) {
        bf16x8 a = *(const bf16x8*)(Wt4f + (((kc * 4 + m) * 64 + l) << 3));
        acc2[m] = __builtin_amdgcn_mfma_f32_16x16x32_bf16(a, bco, acc2[m], 0, 0, 0);
      }
    }
    if (cc < 56) {
      int rc = (rowt + 1) * 58 + cc + 1;        // center cell in sIn
#pragma unroll
      for (int m = 0; m < 4; m++) {
        int cg0 = 2 * m + (l4 >> 1);
        int us = rc * 64 + ((cg0 ^ ((cc + 1) & 7)) << 3) + (l4 & 1) * 4;
        ush4 rv = *(const ush4*)(sIn + us);
        ush4 ov;
#pragma unroll
        for (int r = 0; r < 4; r++) {
          int o = m * 16 + l4 * 4 + r;
          float o2 = fmaxf(fmaf(acc2[m][r], g23[o] * MSC_BNI, b23[o]) + b2f(rv.v[r]), 0.f);
          float v = fmaxf(fmaf(acc[m][t][r], g2[o] * MSC_BNI, b2[o]), 0.f) + o2;
          ov.v[r] = f2b(v);
        }
        *(ush4*)(C2t + gbase + m * 16 + l4 * 4) = ov;
      }
    }
  }
}

// K7: 1x1 conv 64->256 via MFMA GEMM + BN + x-residual + ReLU -> d_out fp32.
__global__ __launch_bounds__(256, 3) void k7_mfma(
    const unsigned short* C2t, const float* x, float* outp,
    const unsigned short* Wt3f, const float* g, const float* bb) {
  __shared__ float sOut[64 * 68];               // 17,408 B
  int n = blockIdx.x / 49;
  int hw0 = (blockIdx.x % 49) * 64;
  int l = threadIdx.x & 63;
  int wv = threadIdx.x >> 6;                    // 0..3
  int l15 = l & 15, l4 = l >> 4;
  f32x4 acc[4][4];
#pragma unroll
  for (int m = 0; m < 4; m++)
#pragma unroll
    for (int t = 0; t < 4; t++) acc[m][t] = (f32x4){0.f, 0.f, 0.f, 0.f};

#pragma unroll
  for (int kc = 0; kc < 2; kc++) {
    bf16x8 a[4];
#pragma unroll
    for (int m = 0; m < 4; m++)
      a[m] = *(const bf16x8*)(Wt3f + (((kc * 16 + wv * 4 + m) * 64 + l) << 3));
#pragma unroll
    for (int t = 0; t < 4; t++) {
      int colt = t * 16 + l15;
      bf16x8 b = *(const bf16x8*)(C2t + ((size_t)n * 3136 + hw0 + colt) * 64 + kc * 32 + l4 * 8);
#pragma unroll
      for (int m = 0; m < 4; m++)
        acc[m][t] = __builtin_amdgcn_mfma_f32_16x16x32_bf16(a[m], b, acc[m][t], 0, 0, 0);
    }
  }

  // epilogue: 4 passes; pass m covers o = wv*64 + m*16 + [0,16) for wv 0..3.
  for (int m = 0; m < 4; m++) {
#pragma unroll
    for (int t = 0; t < 4; t++)
#pragma unroll
      for (int r = 0; r < 4; r++)
        sOut[(wv * 16 + l4 * 4 + r) * 68 + t * 16 + l15] = acc[m][t][r];
    __syncthreads();
#pragma unroll
    for (int s = 0; s < 4; s++) {
      int ro = (threadIdx.x >> 4) + s * 16;     // 0..63
      int o = (ro >> 4) * 64 + m * 16 + (ro & 15);
      int colq = (threadIdx.x & 15) * 4;
      float4 v = *(float4*)&sOut[ro * 68 + colq];
      int off = (n * 256 + o) * 3136 + hw0 + colq;
      float4 xv = *(const float4*)(x + off);
      float sg = g[o] * MSC_BNI, bo = bb[o];
      float4 ov;
      ov.x = fmaxf(fmaf(v.x, sg, bo) + xv.x, 0.f);
      ov.y = fmaxf(fmaf(v.y, sg, bo) + xv.y, 0.f);
      ov.z = fmaxf(fmaf(v.z, sg, bo) + xv.z, 0.f);
      ov.w = fmaxf(fmaf(v.w, sg, bo) + xv.w, 0.f);
      *(float4*)(outp + off) = ov;
    }
    __syncthreads();
  }
}

extern "C" void kernel_launch(void* const* d_in, const int* in_sizes, int n_in,
                              void* d_out, int out_size, void* d_ws, size_t ws_size,
                              hipStream_t stream) {
  const float* x        = (const float*)d_in[0];
  const float* w1       = (const float*)d_in[1];
  const float* w3       = (const float*)d_in[2];
  const float* w5       = (const float*)d_in[3];
  const float* w7       = (const float*)d_in[4];
  const float* w_conv1  = (const float*)d_in[5];
  const float* g1       = (const float*)d_in[6];
  const float* b1       = (const float*)d_in[7];
  const float* w_conv21 = (const float*)d_in[8];
  const float* g21      = (const float*)d_in[9];
  const float* b21      = (const float*)d_in[10];
  const float* g22      = (const float*)d_in[11];
  const float* b22      = (const float*)d_in[12];
  const float* w_conv22 = (const float*)d_in[13];
  const float* g23      = (const float*)d_in[14];
  const float* b23      = (const float*)d_in[15];
  const float* w_conv2  = (const float*)d_in[16];
  const float* g2       = (const float*)d_in[17];
  const float* b2       = (const float*)d_in[18];
  const float* w_conv3  = (const float*)d_in[19];
  const float* g3       = (const float*)d_in[20];
  const float* b3       = (const float*)d_in[21];

  // d_out (fp32, 205,520,896 B) scratch map (all dead before K7's rewrite):
  //   Yt   fp32 [0 .. 12,845,056)             K12 w, K4 r  [n][hw][16]
  //   COt  bf16 [12,845,056 .. 38,535,168)    K4 w, K56 r  [n][hw][64]
  //   R2t  bf16 [103,563,264 .. 129,253,376)  K12 w; K56 r [n][hw][64]
  //   Wt2f bf16 [134,217,728 .. +73,728)      K0 w, K56 r
  //   Wt1f bf16 [134,291,456 .. +32,768)      K0 w, K12 r
  //   Wt4f bf16 [134,324,224 .. +8,192)       K0 w, K56 r
  //   Wt5f bf16 [134,332,416 .. +2,048)       K0 w, K12 r
  // d_ws:
  //   C2t  bf16 [0 .. 25,690,112)             K56 w, K7 r  [n][hw][64]
  //   Wt3f bf16 [25,690,112 .. +32,768)       K0 w, K7 r (K7 overwrites d_out)
  char* ob = (char*)d_out;
  char* ws = (char*)d_ws;
  float*          Yt   = (float*)ob;
  unsigned short* COt  = (unsigned short*)(ob + 12845056);
  unsigned short* R2t  = (unsigned short*)(ob + 103563264);
  unsigned short* Wt2f = (unsigned short*)(ob + 134217728);
  unsigned short* Wt1f = (unsigned short*)(ob + 134291456);
  unsigned short* Wt4f = (unsigned short*)(ob + 134324224);
  unsigned short* Wt5f = (unsigned short*)(ob + 134332416);
  unsigned short* C2t  = (unsigned short*)ws;
  unsigned short* Wt3f = (unsigned short*)(ws + 25690112);

  k0_prep  <<<dim3(292),     dim3(256), 0, stream>>>(w_conv1, w_conv2, w_conv3, w_conv22,
                                                     w_conv21, Wt1f, Wt2f, Wt3f, Wt4f, Wt5f);
  k12_fused<<<dim3(8 * 98),  dim3(256), 0, stream>>>(x, R2t, Yt, Wt1f, Wt5f,
                                                     w1, w3, w5, w7, g1, b1, g21, b21);
  k4_corr  <<<dim3(64 * 14), dim3(256), 0, stream>>>(Yt, COt, g22, b22);
  k56_mfma <<<dim3(64 * 14), dim3(256), 0, stream>>>(R2t, COt, C2t, Wt2f, Wt4f, g2, b2, g23, b23);
  k7_mfma  <<<dim3(64 * 49), dim3(256), 0, stream>>>(C2t, x, (float*)d_out, Wt3f, g3, b3);
}